// Round 1
// baseline (191.320 us; speedup 1.0000x reference)
//
#include <hip/hip_runtime.h>
#include <math.h>

#define NN_ 256      // nodes per graph
#define BB_ 64       // batch
#define FF_ 5        // features
#define NE_ 65536    // NN_*NN_
#define NBF 16384    // BB_*NN_  (stride of one feature plane in transposed layout)
#define ALPHA_ 0.1f
#define BETA_ 0.45f  // (1-ALPHA)/K

// workspace layout in floats
#define OFF_W      0
#define OFF_DIS    65536
#define OFF_LOGITS 65792
#define OFF_A      66048
#define OFF_M0     131584
#define OFF_M1     197120
#define OFF_M2     262656
#define OFF_XA     328192
#define OFF_XB     410112
// total 492032 floats = ~1.97 MB

// ---------------------------------------------------------------------------
// Kernel 1: build dense symmetric W from tril params, row sums -> dis,
// plus (block 0, lane 0) the per-layer scalar math: a,b,pi,logits,kld.
// ---------------------------------------------------------------------------
__global__ __launch_bounds__(256) void build_w_dis(
    const float* __restrict__ p, const float* __restrict__ a_uc,
    const float* __restrict__ b_uc, const float* __restrict__ u_pi,
    float* __restrict__ ws, float* __restrict__ out) {
  const int i = blockIdx.x, j = threadIdx.x;
  const int t = (i >= j) ? (i * (i + 1) / 2 + j) : (j * (j + 1) / 2 + i);
  const float w = p[t];
  ws[OFF_W + i * NN_ + j] = w;

  __shared__ float red[NN_];
  red[j] = fabsf(w);
  __syncthreads();
  for (int s = NN_ / 2; s > 0; s >>= 1) {
    if (j < s) red[j] += red[j + s];
    __syncthreads();
  }
  if (j == 0) {
    const float deg = red[0];
    ws[OFF_DIS + i] = (deg > 0.0f) ? (1.0f / sqrtf(deg)) : 0.0f;
  }

  if (i == 0 && j == 0) {
    double kld_sum = 0.0;
    const double euler = 0.577215664901532;
    for (int l = 0; l < 3; ++l) {
      double au = (double)a_uc[l]; if (au < -10.0) au = -10.0;
      double bu = (double)b_uc[l]; if (bu < -10.0) bu = -10.0; if (bu > 50.0) bu = 50.0;
      const double a = log1p(exp(au));
      const double b = log1p(exp(bu));
      double up = (double)u_pi[l];
      up = fmin(fmax(up, 1e-6), 1.0 - 1e-6);
      const double pi = pow(1.0 - pow(up, 1.0 / b), 1.0 / a);
      const double logits = log(pi) - log1p(-pi);
      ws[OFF_LOGITS + l] = (float)logits;
      out[193 + l] = (float)pi;  // drop_rates
      // digamma(b): shift to x>=6, asymptotic series
      double x = b, dg = 0.0;
      while (x < 6.0) { dg -= 1.0 / x; x += 1.0; }
      const double inv = 1.0 / x, inv2 = inv * inv;
      dg += log(x) - 0.5 * inv
            - inv2 * (1.0 / 12.0 - inv2 * (1.0 / 120.0 - inv2 * (1.0 / 252.0)));
      kld_sum += (1.0 - 0.8 / a) * (-euler - dg - 1.0 / b)
                 + log(a * b + 1e-10) - log(0.8) - (b - 1.0) / b;
    }
    out[192] = (float)kld_sum;  // kld_loss
  }
}

// ---------------------------------------------------------------------------
// Kernel 2: adjacency A = dis_i * W * dis_j, and M_l = sigmoid(...)*A, l=0..2
// ---------------------------------------------------------------------------
__global__ __launch_bounds__(256) void build_mats(
    const float* __restrict__ u_rb, float* __restrict__ ws) {
  const int i = blockIdx.x, j = threadIdx.x;
  const int idx = i * NN_ + j;
  const float adj = ws[OFF_DIS + i] * ws[OFF_W + idx] * ws[OFF_DIS + j];
  ws[OFF_A + idx] = adj;
  const float lg0 = ws[OFF_LOGITS + 0];
  const float lg1 = ws[OFF_LOGITS + 1];
  const float lg2 = ws[OFF_LOGITS + 2];
  const float inv_temp = 1.0f / 0.6f;

  float u, v, z;
  u = fminf(fmaxf(u_rb[0 * NE_ + idx], 1e-6f), 1.0f - 1e-6f);
  v = (lg0 + logf(u) - log1pf(-u)) * inv_temp;
  z = 1.0f / (1.0f + expf(-v));
  ws[OFF_M0 + idx] = z * adj;

  u = fminf(fmaxf(u_rb[1 * NE_ + idx], 1e-6f), 1.0f - 1e-6f);
  v = (lg1 + logf(u) - log1pf(-u)) * inv_temp;
  z = 1.0f / (1.0f + expf(-v));
  ws[OFF_M1 + idx] = z * adj;

  u = fminf(fmaxf(u_rb[2 * NE_ + idx], 1e-6f), 1.0f - 1e-6f);
  v = (lg2 + logf(u) - log1pf(-u)) * inv_temp;
  z = 1.0f / (1.0f + expf(-v));
  ws[OFF_M2 + idx] = z * adj;
}

// ---------------------------------------------------------------------------
// Conv step: Y = ALPHA*X + BETA * M^T X, per batch. Grid 256 blocks x 64 thr:
// block = (batch b, j-quarter). Lane = output node j. M reads coalesced;
// X reads wave-uniform (scalar-load friendly). Output in transposed [f][b][i].
// T_IN: input in transposed layout (else original x layout [b*N+i][f]).
// ---------------------------------------------------------------------------
template <bool T_IN, bool RELU>
__global__ __launch_bounds__(64) void conv_step(
    const float* __restrict__ M, const float* __restrict__ X,
    float* __restrict__ Y) {
  const int b = blockIdx.x >> 2;
  const int j = ((blockIdx.x & 3) << 6) | threadIdx.x;

  float a0 = 0.f, a1 = 0.f, a2 = 0.f, a3 = 0.f, a4 = 0.f;
  float s0, s1, s2, s3, s4;

  if (T_IN) {
    const float* __restrict__ x0 = X + 0 * NBF + b * NN_;
    const float* __restrict__ x1 = X + 1 * NBF + b * NN_;
    const float* __restrict__ x2 = X + 2 * NBF + b * NN_;
    const float* __restrict__ x3 = X + 3 * NBF + b * NN_;
    const float* __restrict__ x4 = X + 4 * NBF + b * NN_;
#pragma unroll 8
    for (int i = 0; i < NN_; ++i) {
      const float w = M[i * NN_ + j];
      a0 += w * x0[i]; a1 += w * x1[i]; a2 += w * x2[i];
      a3 += w * x3[i]; a4 += w * x4[i];
    }
    s0 = x0[j]; s1 = x1[j]; s2 = x2[j]; s3 = x3[j]; s4 = x4[j];
  } else {
    const float* __restrict__ xb = X + b * (NN_ * FF_);
#pragma unroll 8
    for (int i = 0; i < NN_; ++i) {
      const float w = M[i * NN_ + j];
      const float* __restrict__ xr = xb + i * FF_;
      a0 += w * xr[0]; a1 += w * xr[1]; a2 += w * xr[2];
      a3 += w * xr[3]; a4 += w * xr[4];
    }
    s0 = xb[j * FF_ + 0]; s1 = xb[j * FF_ + 1]; s2 = xb[j * FF_ + 2];
    s3 = xb[j * FF_ + 3]; s4 = xb[j * FF_ + 4];
  }

  float y0 = ALPHA_ * s0 + BETA_ * a0;
  float y1 = ALPHA_ * s1 + BETA_ * a1;
  float y2 = ALPHA_ * s2 + BETA_ * a2;
  float y3 = ALPHA_ * s3 + BETA_ * a3;
  float y4 = ALPHA_ * s4 + BETA_ * a4;
  if (RELU) {
    y0 = fmaxf(y0, 0.f); y1 = fmaxf(y1, 0.f); y2 = fmaxf(y2, 0.f);
    y3 = fmaxf(y3, 0.f); y4 = fmaxf(y4, 0.f);
  }
  Y[0 * NBF + b * NN_ + j] = y0;
  Y[1 * NBF + b * NN_ + j] = y1;
  Y[2 * NBF + b * NN_ + j] = y2;
  Y[3 * NBF + b * NN_ + j] = y3;
  Y[4 * NBF + b * NN_ + j] = y4;
}

// ---------------------------------------------------------------------------
// Head: out = relu(O @ lin_w + lin_b); pooled = sum_j out; output = pooled@fc+b
// O in transposed layout. 64 blocks (batch) x 256 threads (2 halves x 128 k).
// ---------------------------------------------------------------------------
__global__ __launch_bounds__(256) void head_kernel(
    const float* __restrict__ O, const float* __restrict__ lin_w,
    const float* __restrict__ lin_b, const float* __restrict__ fc_w,
    const float* __restrict__ fc_b, float* __restrict__ out) {
  const int b = blockIdx.x, tid = threadIdx.x;
  const int k = tid & 127, h = tid >> 7;

  const float* __restrict__ o0 = O + 0 * NBF + b * NN_;
  const float* __restrict__ o1 = O + 1 * NBF + b * NN_;
  const float* __restrict__ o2 = O + 2 * NBF + b * NN_;
  const float* __restrict__ o3 = O + 3 * NBF + b * NN_;
  const float* __restrict__ o4 = O + 4 * NBF + b * NN_;

  const float lw0 = lin_w[0 * 128 + k];
  const float lw1 = lin_w[1 * 128 + k];
  const float lw2 = lin_w[2 * 128 + k];
  const float lw3 = lin_w[3 * 128 + k];
  const float lw4 = lin_w[4 * 128 + k];
  const float lb = lin_b[k];

  float acc = 0.f;
  const int j0 = h * 128;
#pragma unroll 4
  for (int j = j0; j < j0 + 128; ++j) {
    const float v = lb + lw0 * o0[j] + lw1 * o1[j] + lw2 * o2[j] +
                    lw3 * o3[j] + lw4 * o4[j];
    acc += fmaxf(v, 0.f);
  }

  __shared__ float pool2[256];
  __shared__ float pool[128];
  pool2[h * 128 + k] = acc;
  __syncthreads();
  if (h == 0) pool[k] = pool2[k] + pool2[128 + k];
  __syncthreads();
  if (tid < 3) {
    float s = fc_b[tid];
    for (int kk = 0; kk < 128; ++kk) s += pool[kk] * fc_w[kk * 3 + tid];
    out[b * 3 + tid] = s;
  }
}

// ---------------------------------------------------------------------------
extern "C" void kernel_launch(void* const* d_in, const int* in_sizes, int n_in,
                              void* d_out, int out_size, void* d_ws,
                              size_t ws_size, hipStream_t stream) {
  const float* x      = (const float*)d_in[0];
  const float* p      = (const float*)d_in[1];
  const float* a_uc   = (const float*)d_in[2];
  const float* b_uc   = (const float*)d_in[3];
  const float* u_pi   = (const float*)d_in[4];
  const float* u_rb   = (const float*)d_in[5];
  const float* lin_w  = (const float*)d_in[6];
  const float* lin_b  = (const float*)d_in[7];
  const float* fc_w   = (const float*)d_in[8];
  const float* fc_b   = (const float*)d_in[9];
  // d_in[10] edge_index, d_in[11] batch: fully deterministic, never read.
  float* out = (float*)d_out;
  float* ws  = (float*)d_ws;

  build_w_dis<<<256, 256, 0, stream>>>(p, a_uc, b_uc, u_pi, ws, out);
  build_mats<<<256, 256, 0, stream>>>(u_rb, ws);

  // chain: x -> (M0) xa -> (A) xb -> (M1,relu) xa -> (A) xb -> (M2) xa
  conv_step<false, false><<<256, 64, 0, stream>>>(ws + OFF_M0, x, ws + OFF_XA);
  conv_step<true,  false><<<256, 64, 0, stream>>>(ws + OFF_A,  ws + OFF_XA, ws + OFF_XB);
  conv_step<true,  true ><<<256, 64, 0, stream>>>(ws + OFF_M1, ws + OFF_XB, ws + OFF_XA);
  conv_step<true,  false><<<256, 64, 0, stream>>>(ws + OFF_A,  ws + OFF_XA, ws + OFF_XB);
  conv_step<true,  false><<<256, 64, 0, stream>>>(ws + OFF_M2, ws + OFF_XB, ws + OFF_XA);

  head_kernel<<<64, 256, 0, stream>>>(ws + OFF_XA, lin_w, lin_b, fc_w, fc_b, out);
}

// Round 2
// 176.368 us; speedup vs baseline: 1.0848x; 1.0848x over previous
//
#include <hip/hip_runtime.h>
#include <math.h>

#define NN_ 256      // nodes per graph
#define BB_ 64       // batch
#define FF_ 5        // features
#define NE_ 65536    // NN_*NN_

// workspace layout in floats
#define OFF_W      0
#define OFF_DIS    65536
#define OFF_LOGITS 65792
#define OFF_A      66048
#define OFF_M0     131584
#define OFF_M1     197120
#define OFF_M2     262656
#define OFF_XBUF   328192   // 2 buffers * 64 batches * 256 rows * 8 floats = 262144
// total ~590K floats = 2.4 MB (ws is 256 MiB)

// ---------------------------------------------------------------------------
// K1: dense symmetric W from tril params, row sums -> dis; lane (0,0) does the
// per-layer scalar math (a,b,pi,logits,kld) in fp32 (threshold is ~2e-2 abs).
// ---------------------------------------------------------------------------
__global__ __launch_bounds__(256) void build_w_dis(
    const float* __restrict__ p, const float* __restrict__ a_uc,
    const float* __restrict__ b_uc, const float* __restrict__ u_pi,
    float* __restrict__ ws, float* __restrict__ out) {
  const int i = blockIdx.x, j = threadIdx.x;
  const int t = (i >= j) ? (i * (i + 1) / 2 + j) : (j * (j + 1) / 2 + i);
  const float w = p[t];
  ws[OFF_W + i * NN_ + j] = w;

  __shared__ float red[NN_];
  red[j] = fabsf(w);
  __syncthreads();
  for (int s = NN_ / 2; s > 0; s >>= 1) {
    if (j < s) red[j] += red[j + s];
    __syncthreads();
  }
  if (j == 0) {
    const float deg = red[0];
    ws[OFF_DIS + i] = (deg > 0.0f) ? (1.0f / sqrtf(deg)) : 0.0f;
  }

  if (i == 0 && j == 0) {
    float kld_sum = 0.0f;
    const float euler = 0.577215664901532f;
    for (int l = 0; l < 3; ++l) {
      float au = a_uc[l]; if (au < -10.0f) au = -10.0f;
      float bu = b_uc[l]; if (bu < -10.0f) bu = -10.0f; if (bu > 50.0f) bu = 50.0f;
      const float a = log1pf(expf(au));
      const float b = log1pf(expf(bu));
      float up = u_pi[l];
      up = fminf(fmaxf(up, 1e-6f), 1.0f - 1e-6f);
      const float pi = powf(1.0f - powf(up, 1.0f / b), 1.0f / a);
      const float logits = logf(pi) - log1pf(-pi);
      ws[OFF_LOGITS + l] = logits;
      out[193 + l] = pi;  // drop_rates
      // digamma(b): shift to x>=6, asymptotic series
      float x = b, dg = 0.0f;
      while (x < 6.0f) { dg -= 1.0f / x; x += 1.0f; }
      const float inv = 1.0f / x, inv2 = inv * inv;
      dg += logf(x) - 0.5f * inv
            - inv2 * (1.0f / 12.0f - inv2 * (1.0f / 120.0f - inv2 * (1.0f / 252.0f)));
      kld_sum += (1.0f - 0.8f / a) * (-euler - dg - 1.0f / b)
                 + logf(a * b + 1e-10f) - logf(0.8f) - (b - 1.0f) / b;
    }
    out[192] = kld_sum;  // kld_loss
  }
}

// ---------------------------------------------------------------------------
// K2: A = dis_i * W * dis_j; M_l = sigmoid((logits_l + logit(u))/T) * A
// ---------------------------------------------------------------------------
__global__ __launch_bounds__(256) void build_mats(
    const float* __restrict__ u_rb, float* __restrict__ ws) {
  const int i = blockIdx.x, j = threadIdx.x;
  const int idx = i * NN_ + j;
  const float adj = ws[OFF_DIS + i] * ws[OFF_W + idx] * ws[OFF_DIS + j];
  ws[OFF_A + idx] = adj;
  const float lg0 = ws[OFF_LOGITS + 0];
  const float lg1 = ws[OFF_LOGITS + 1];
  const float lg2 = ws[OFF_LOGITS + 2];
  const float inv_temp = 1.0f / 0.6f;

  float u, v, z;
  u = fminf(fmaxf(u_rb[0 * NE_ + idx], 1e-6f), 1.0f - 1e-6f);
  v = (lg0 + logf(u) - log1pf(-u)) * inv_temp;
  z = 1.0f / (1.0f + expf(-v));
  ws[OFF_M0 + idx] = z * adj;

  u = fminf(fmaxf(u_rb[1 * NE_ + idx], 1e-6f), 1.0f - 1e-6f);
  v = (lg1 + logf(u) - log1pf(-u)) * inv_temp;
  z = 1.0f / (1.0f + expf(-v));
  ws[OFF_M1 + idx] = z * adj;

  u = fminf(fmaxf(u_rb[2 * NE_ + idx], 1e-6f), 1.0f - 1e-6f);
  v = (lg2 + logf(u) - log1pf(-u)) * inv_temp;
  z = 1.0f / (1.0f + expf(-v));
  ws[OFF_M2 + idx] = z * adj;
}

// ---------------------------------------------------------------------------
// K3: all 5 conv layers + MLP head, one block per batch (64 blocks x 1024).
// Thread (q,j): q = i-quarter, j = output node. M reads coalesced across the
// wave; X reads are lane-uniform float4+float broadcasts (rows padded to 8).
// X chains through per-block global scratch (same-CU L1 => workgroup-coherent
// across __syncthreads). Partial i-sums reduced through LDS.
// ---------------------------------------------------------------------------
__global__ __launch_bounds__(1024) void fused_conv_head(
    const float* __restrict__ x0g,
    const float* __restrict__ A,  const float* __restrict__ M0,
    const float* __restrict__ M1, const float* __restrict__ M2,
    float* __restrict__ xbuf,
    const float* __restrict__ lin_w, const float* __restrict__ lin_b,
    const float* __restrict__ fc_w,  const float* __restrict__ fc_b,
    float* __restrict__ out) {
  const int b = blockIdx.x;
  const int tid = threadIdx.x;
  float* Xc = xbuf + b * 2048;
  float* Xn = xbuf + BB_ * 2048 + b * 2048;

  __shared__ float part[4 * 256 * 5];  // 20 KB
  __shared__ float hp[8 * 128];        // 4 KB

  // stage input x (layout [b*256+i][5]) into padded rows [i][8]
  for (int idx = tid; idx < 1280; idx += 1024) {
    const int i = idx / 5, f = idx - 5 * i;
    Xc[i * 8 + f] = x0g[b * 1280 + idx];
  }
  __syncthreads();

  const float* Ms[5] = {M0, A, M1, A, M2};
  const int q = tid >> 8;    // 0..3
  const int j = tid & 255;
  const int i0 = q * 64;

  for (int l = 0; l < 5; ++l) {
    const float* __restrict__ M = Ms[l] + j;
    float a0 = 0.f, a1 = 0.f, a2 = 0.f, a3 = 0.f, a4 = 0.f;
#pragma unroll 8
    for (int i = i0; i < i0 + 64; ++i) {
      const float4 xv = *(const float4*)(Xc + i * 8);
      const float x4 = Xc[i * 8 + 4];
      const float w = M[i * NN_];
      a0 += w * xv.x; a1 += w * xv.y; a2 += w * xv.z;
      a3 += w * xv.w; a4 += w * x4;
    }
    float* pp = part + (q * 256 + j) * 5;
    pp[0] = a0; pp[1] = a1; pp[2] = a2; pp[3] = a3; pp[4] = a4;
    __syncthreads();
    const bool relu = (l == 2);
    for (int idx = tid; idx < 1280; idx += 1024) {
      const int jj = idx / 5, f = idx - 5 * jj;
      const float s = part[idx] + part[1280 + idx] + part[2560 + idx] +
                      part[3840 + idx];
      float y = 0.1f * Xc[jj * 8 + f] + 0.45f * s;
      if (relu) y = fmaxf(y, 0.f);
      Xn[jj * 8 + f] = y;
    }
    __syncthreads();
    float* t = Xc; Xc = Xn; Xn = t;
  }

  // head: Xc holds O (256 x 5, padded rows of 8)
  const int k = tid & 127;
  const int seg = tid >> 7;  // 0..7, each sums 32 j's
  const float lw0 = lin_w[0 * 128 + k];
  const float lw1 = lin_w[1 * 128 + k];
  const float lw2 = lin_w[2 * 128 + k];
  const float lw3 = lin_w[3 * 128 + k];
  const float lw4 = lin_w[4 * 128 + k];
  const float lb = lin_b[k];
  float acc = 0.f;
  const int j0 = seg * 32;
#pragma unroll 4
  for (int jj = j0; jj < j0 + 32; ++jj) {
    const float4 ov = *(const float4*)(Xc + jj * 8);
    const float o4 = Xc[jj * 8 + 4];
    const float v = lb + lw0 * ov.x + lw1 * ov.y + lw2 * ov.z +
                    lw3 * ov.w + lw4 * o4;
    acc += fmaxf(v, 0.f);
  }
  hp[seg * 128 + k] = acc;
  __syncthreads();
  if (tid < 128) {
    float s = 0.f;
#pragma unroll
    for (int s8 = 0; s8 < 8; ++s8) s += hp[s8 * 128 + tid];
    hp[tid] = s;  // pooled[k]
  }
  __syncthreads();
  if (tid < 3) {
    float s = fc_b[tid];
    for (int kk = 0; kk < 128; ++kk) s += hp[kk] * fc_w[kk * 3 + tid];
    out[b * 3 + tid] = s;
  }
}

// ---------------------------------------------------------------------------
extern "C" void kernel_launch(void* const* d_in, const int* in_sizes, int n_in,
                              void* d_out, int out_size, void* d_ws,
                              size_t ws_size, hipStream_t stream) {
  const float* x      = (const float*)d_in[0];
  const float* p      = (const float*)d_in[1];
  const float* a_uc   = (const float*)d_in[2];
  const float* b_uc   = (const float*)d_in[3];
  const float* u_pi   = (const float*)d_in[4];
  const float* u_rb   = (const float*)d_in[5];
  const float* lin_w  = (const float*)d_in[6];
  const float* lin_b  = (const float*)d_in[7];
  const float* fc_w   = (const float*)d_in[8];
  const float* fc_b   = (const float*)d_in[9];
  // d_in[10] edge_index, d_in[11] batch: fully deterministic, never read.
  float* out = (float*)d_out;
  float* ws  = (float*)d_ws;

  build_w_dis<<<256, 256, 0, stream>>>(p, a_uc, b_uc, u_pi, ws, out);
  build_mats<<<256, 256, 0, stream>>>(u_rb, ws);
  fused_conv_head<<<64, 1024, 0, stream>>>(
      x, ws + OFF_A, ws + OFF_M0, ws + OFF_M1, ws + OFF_M2, ws + OFF_XBUF,
      lin_w, lin_b, fc_w, fc_b, out);
}

// Round 3
// 168.132 us; speedup vs baseline: 1.1379x; 1.0490x over previous
//
#include <hip/hip_runtime.h>
#include <math.h>

#define NN_ 256      // nodes per graph
#define BB_ 64       // batch
#define FF_ 5        // features
#define NE_ 65536    // NN_*NN_
#define NBF_ 320     // BB_*FF_  (stacked batch*feature columns)

// workspace layout in floats
#define OFF_W      0
#define OFF_DIS    65536
#define OFF_LOGITS 65792
#define OFF_GA     66048   // L_A  = 0.1 I + 0.45 A^T      (row-major)
#define OFF_G1     131584  // L_1  from M0
#define OFF_G3     197120  // L_3  from M1
#define OFF_G5     262656  // L_5  from M2
#define OFF_T1     328192  // GA * G1
#define OFF_T2     393728  // G5 * GA   (= composed post-relu operator C2)
#define OFF_C1     459264  // G3 * T1   (= composed pre-relu operator)
#define OFF_XT     524800  // X  transposed: [k=node][b*5+f], 256 x 320
#define OFF_Y3     606720  // relu(C1 * XT), 256 x 320
#define OFF_O      688640  // T2 * Y3,      256 x 320
// end 770560 floats = 3.08 MB

// ---------------------------------------------------------------------------
// K1: dense symmetric W from tril params, row |sums| -> dis; lane (0,0) does
// the per-layer scalar math (a,b,pi,logits,kld) in fp32.
// ---------------------------------------------------------------------------
__global__ __launch_bounds__(256) void build_w_dis(
    const float* __restrict__ p, const float* __restrict__ a_uc,
    const float* __restrict__ b_uc, const float* __restrict__ u_pi,
    float* __restrict__ ws, float* __restrict__ out) {
  const int i = blockIdx.x, j = threadIdx.x;
  const int t = (i >= j) ? (i * (i + 1) / 2 + j) : (j * (j + 1) / 2 + i);
  const float w = p[t];
  ws[OFF_W + i * NN_ + j] = w;

  __shared__ float red[NN_];
  red[j] = fabsf(w);
  __syncthreads();
  for (int s = NN_ / 2; s > 0; s >>= 1) {
    if (j < s) red[j] += red[j + s];
    __syncthreads();
  }
  if (j == 0) {
    const float deg = red[0];
    ws[OFF_DIS + i] = (deg > 0.0f) ? (1.0f / sqrtf(deg)) : 0.0f;
  }

  if (i == 0 && j == 0) {
    float kld_sum = 0.0f;
    const float euler = 0.577215664901532f;
    for (int l = 0; l < 3; ++l) {
      float au = a_uc[l]; if (au < -10.0f) au = -10.0f;
      float bu = b_uc[l]; if (bu < -10.0f) bu = -10.0f; if (bu > 50.0f) bu = 50.0f;
      const float a = log1pf(expf(au));
      const float b = log1pf(expf(bu));
      float up = u_pi[l];
      up = fminf(fmaxf(up, 1e-6f), 1.0f - 1e-6f);
      const float pi = powf(1.0f - powf(up, 1.0f / b), 1.0f / a);
      const float logits = logf(pi) - log1pf(-pi);
      ws[OFF_LOGITS + l] = logits;
      out[193 + l] = pi;  // drop_rates
      float x = b, dg = 0.0f;
      while (x < 6.0f) { dg -= 1.0f / x; x += 1.0f; }
      const float inv = 1.0f / x, inv2 = inv * inv;
      dg += logf(x) - 0.5f * inv
            - inv2 * (1.0f / 12.0f - inv2 * (1.0f / 120.0f - inv2 * (1.0f / 252.0f)));
      kld_sum += (1.0f - 0.8f / a) * (-euler - dg - 1.0f / b)
                 + logf(a * b + 1e-10f) - logf(0.8f) - (b - 1.0f) / b;
    }
    out[192] = kld_sum;  // kld_loss
  }
}

// ---------------------------------------------------------------------------
// K2: per row i of M: adj = dis_i W_ij dis_j, z_l = sigmoid(...). Emit the
// four conv OPERATORS row-major: G[j][i] = 0.1*(i==j) + 0.45*M[i][j]
// (i.e. L = 0.1 I + 0.45 M^T, scatter-written by column). Also transpose x
// into XT[k][b*5+f].
// ---------------------------------------------------------------------------
__global__ __launch_bounds__(256) void build_ops(
    const float* __restrict__ u_rb, const float* __restrict__ x0g,
    float* __restrict__ ws) {
  const int i = blockIdx.x, j = threadIdx.x;
  const int idx = i * NN_ + j;
  const float adj = ws[OFF_DIS + i] * ws[OFF_W + idx] * ws[OFF_DIS + j];
  const float dlt = (i == j) ? 0.1f : 0.0f;
  const float lg0 = ws[OFF_LOGITS + 0];
  const float lg1 = ws[OFF_LOGITS + 1];
  const float lg2 = ws[OFF_LOGITS + 2];
  const float inv_temp = 1.0f / 0.6f;
  const int tcol = j * NN_ + i;  // transposed position

  ws[OFF_GA + tcol] = 0.45f * adj + dlt;

  float u, v, z;
  u = fminf(fmaxf(u_rb[0 * NE_ + idx], 1e-6f), 1.0f - 1e-6f);
  v = (lg0 + logf(u) - log1pf(-u)) * inv_temp;
  z = 1.0f / (1.0f + expf(-v));
  ws[OFF_G1 + tcol] = 0.45f * z * adj + dlt;

  u = fminf(fmaxf(u_rb[1 * NE_ + idx], 1e-6f), 1.0f - 1e-6f);
  v = (lg1 + logf(u) - log1pf(-u)) * inv_temp;
  z = 1.0f / (1.0f + expf(-v));
  ws[OFF_G3 + tcol] = 0.45f * z * adj + dlt;

  u = fminf(fmaxf(u_rb[2 * NE_ + idx], 1e-6f), 1.0f - 1e-6f);
  v = (lg2 + logf(u) - log1pf(-u)) * inv_temp;
  z = 1.0f / (1.0f + expf(-v));
  ws[OFF_G5 + tcol] = 0.45f * z * adj + dlt;

  // XT row i: XT[i*320 + (b*5+f)] = x[b*1280 + i*5 + f]
  for (int t = j; t < NBF_; t += NN_) {
    const int b = t / FF_, f = t - FF_ * b;
    ws[OFF_XT + i * NBF_ + t] = x0g[b * (NN_ * FF_) + i * FF_ + f];
  }
}

// ---------------------------------------------------------------------------
// 256x256x256 GEMM body: block computes 4 rows x 64 cols. A-row reads are
// wave-uniform float4 broadcasts; B reads coalesced. Two accumulator sets
// break the FMA dependency chain.
// ---------------------------------------------------------------------------
__device__ __forceinline__ void gemm4r_body(
    const float* __restrict__ A, const float* __restrict__ B,
    float* __restrict__ C, int i0, int j) {
  float acc0[4] = {0.f, 0.f, 0.f, 0.f};
  float acc1[4] = {0.f, 0.f, 0.f, 0.f};
#pragma unroll 2
  for (int k = 0; k < NN_; k += 8) {
    const float b0 = B[(k + 0) * NN_ + j];
    const float b1 = B[(k + 1) * NN_ + j];
    const float b2 = B[(k + 2) * NN_ + j];
    const float b3 = B[(k + 3) * NN_ + j];
    const float b4 = B[(k + 4) * NN_ + j];
    const float b5 = B[(k + 5) * NN_ + j];
    const float b6 = B[(k + 6) * NN_ + j];
    const float b7 = B[(k + 7) * NN_ + j];
#pragma unroll
    for (int r = 0; r < 4; ++r) {
      const float4 a0 = *(const float4*)(A + (i0 + r) * NN_ + k);
      const float4 a1 = *(const float4*)(A + (i0 + r) * NN_ + k + 4);
      acc0[r] += a0.x * b0 + a0.y * b1 + a0.z * b2 + a0.w * b3;
      acc1[r] += a1.x * b4 + a1.y * b5 + a1.z * b6 + a1.w * b7;
    }
  }
#pragma unroll
  for (int r = 0; r < 4; ++r) C[(i0 + r) * NN_ + j] = acc0[r] + acc1[r];
}

// K3: two independent matmuls in one launch: T1 = GA*G1, T2 = G5*GA.
__global__ __launch_bounds__(64) void gemm_pair(float* __restrict__ ws) {
  const int bid = blockIdx.x;
  const int sel = bid >> 8;
  const int rest = bid & 255;
  const int i0 = (rest >> 2) * 4;
  const int j = ((rest & 3) << 6) | threadIdx.x;
  const float* A = ws + (sel ? OFF_G5 : OFF_GA);
  const float* B = ws + (sel ? OFF_GA : OFF_G1);
  float* C = ws + (sel ? OFF_T2 : OFF_T1);
  gemm4r_body(A, B, C, i0, j);
}

// K4: C1 = G3 * T1.
__global__ __launch_bounds__(64) void gemm_single(float* __restrict__ ws) {
  const int bid = blockIdx.x;
  const int i0 = (bid >> 2) * 4;
  const int j = ((bid & 3) << 6) | threadIdx.x;
  gemm4r_body(ws + OFF_G3, ws + OFF_T1, ws + OFF_C1, i0, j);
}

// ---------------------------------------------------------------------------
// K5/K6: Y[i][bf] = (relu?)( sum_k A[i][k] * X[k][bf] ), 256 x 320 x 256.
// One block per output row i; 320 threads over bf columns.
// ---------------------------------------------------------------------------
template <bool RELU>
__global__ __launch_bounds__(320) void gemm_nb(
    const float* __restrict__ A, const float* __restrict__ X,
    float* __restrict__ Y) {
  const int i = blockIdx.x;
  const int bf = threadIdx.x;
  float acc0 = 0.f, acc1 = 0.f;
#pragma unroll 4
  for (int k = 0; k < NN_; k += 8) {
    const float4 c0 = *(const float4*)(A + i * NN_ + k);
    const float4 c1 = *(const float4*)(A + i * NN_ + k + 4);
    const float x0 = X[(k + 0) * NBF_ + bf];
    const float x1 = X[(k + 1) * NBF_ + bf];
    const float x2 = X[(k + 2) * NBF_ + bf];
    const float x3 = X[(k + 3) * NBF_ + bf];
    const float x4 = X[(k + 4) * NBF_ + bf];
    const float x5 = X[(k + 5) * NBF_ + bf];
    const float x6 = X[(k + 6) * NBF_ + bf];
    const float x7 = X[(k + 7) * NBF_ + bf];
    acc0 += c0.x * x0 + c0.y * x1 + c0.z * x2 + c0.w * x3;
    acc1 += c1.x * x4 + c1.y * x5 + c1.z * x6 + c1.w * x7;
  }
  float y = acc0 + acc1;
  if (RELU) y = fmaxf(y, 0.f);
  Y[i * NBF_ + bf] = y;
}

// ---------------------------------------------------------------------------
// K7: head. out = relu(O @ lin_w + lin_b); pooled = sum_nodes; out @ fc + b.
// O layout [node][b*5+f]. 64 blocks (batch) x 256 threads (2 segs x 128 k).
// ---------------------------------------------------------------------------
__global__ __launch_bounds__(256) void head_kernel(
    const float* __restrict__ O, const float* __restrict__ lin_w,
    const float* __restrict__ lin_b, const float* __restrict__ fc_w,
    const float* __restrict__ fc_b, float* __restrict__ out) {
  const int b = blockIdx.x, tid = threadIdx.x;
  const int k = tid & 127, seg = tid >> 7;

  const float lw0 = lin_w[0 * 128 + k];
  const float lw1 = lin_w[1 * 128 + k];
  const float lw2 = lin_w[2 * 128 + k];
  const float lw3 = lin_w[3 * 128 + k];
  const float lw4 = lin_w[4 * 128 + k];
  const float lb = lin_b[k];

  float acc = 0.f;
  const int j0 = seg * 128;
#pragma unroll 4
  for (int jj = j0; jj < j0 + 128; ++jj) {
    const float* __restrict__ o = O + jj * NBF_ + b * FF_;
    const float v = lb + lw0 * o[0] + lw1 * o[1] + lw2 * o[2] +
                    lw3 * o[3] + lw4 * o[4];
    acc += fmaxf(v, 0.f);
  }

  __shared__ float hp[2 * 128];
  hp[seg * 128 + k] = acc;
  __syncthreads();
  if (tid < 128) hp[tid] += hp[128 + tid];  // pooled[k]
  __syncthreads();
  if (tid < 3) {
    float s = fc_b[tid];
    for (int kk = 0; kk < 128; ++kk) s += hp[kk] * fc_w[kk * 3 + tid];
    out[b * 3 + tid] = s;
  }
}

// ---------------------------------------------------------------------------
extern "C" void kernel_launch(void* const* d_in, const int* in_sizes, int n_in,
                              void* d_out, int out_size, void* d_ws,
                              size_t ws_size, hipStream_t stream) {
  const float* x      = (const float*)d_in[0];
  const float* p      = (const float*)d_in[1];
  const float* a_uc   = (const float*)d_in[2];
  const float* b_uc   = (const float*)d_in[3];
  const float* u_pi   = (const float*)d_in[4];
  const float* u_rb   = (const float*)d_in[5];
  const float* lin_w  = (const float*)d_in[6];
  const float* lin_b  = (const float*)d_in[7];
  const float* fc_w   = (const float*)d_in[8];
  const float* fc_b   = (const float*)d_in[9];
  // d_in[10] edge_index, d_in[11] batch: fully deterministic, never read.
  float* out = (float*)d_out;
  float* ws  = (float*)d_ws;

  build_w_dis<<<256, 256, 0, stream>>>(p, a_uc, b_uc, u_pi, ws, out);
  build_ops<<<256, 256, 0, stream>>>(u_rb, x, ws);
  gemm_pair<<<512, 64, 0, stream>>>(ws);       // T1 = GA*G1 ; T2 = G5*GA
  gemm_single<<<256, 64, 0, stream>>>(ws);     // C1 = G3*T1
  gemm_nb<true><<<256, NBF_, 0, stream>>>(ws + OFF_C1, ws + OFF_XT, ws + OFF_Y3);
  gemm_nb<false><<<256, NBF_, 0, stream>>>(ws + OFF_T2, ws + OFF_Y3, ws + OFF_O);
  head_kernel<<<64, 256, 0, stream>>>(ws + OFF_O, lin_w, lin_b, fc_w, fc_b, out);
}